// Round 1
// baseline (591.987 us; speedup 1.0000x reference)
//
#include <hip/hip_runtime.h>
#include <hip/hip_bf16.h>
#include <hip/hip_fp16.h>

#define D_ 1024
#define H_ 4096
#define NTOK 16384
#define MPAD 16512  // NTOK + 128 (padding so each 128-row tile is single-expert)

typedef __attribute__((ext_vector_type(8))) short bf16x8;
typedef __attribute__((ext_vector_type(4))) float f32x4;

static __device__ __forceinline__ unsigned short f2bf(float f) {
  union { float f; unsigned u; } x; x.f = f;
  unsigned u = x.u + 0x7fffu + ((x.u >> 16) & 1u);  // RNE
  return (unsigned short)(u >> 16);
}

static __device__ __forceinline__ void gld16(const void* g, void* l) {
  __builtin_amdgcn_global_load_lds(
      (const __attribute__((address_space(1))) unsigned int*)g,
      (__attribute__((address_space(3))) unsigned int*)l, 16, 0, 0);
}

// tanh-form gelu reduced to x*sigmoid(2c(x+0.044715x^3)); |err vs exact| ~1e-3
static __device__ __forceinline__ float gelu_fast(float x) {
  const float z = x * (1.5957691216f + 0.0713548163f * x * x);
  return x * __builtin_amdgcn_rcpf(1.0f + __expf(-z));
}

// ---------------- merged transpose fp32 (R x C) -> bf16 (C x R), 4 matrices ----
__global__ __launch_bounds__(256) void transpose4_kernel(
    const float* __restrict__ w1r, const float* __restrict__ w1e,
    const float* __restrict__ w2r, const float* __restrict__ w2e,
    unsigned short* __restrict__ o1r, unsigned short* __restrict__ o1e,
    unsigned short* __restrict__ o2r, unsigned short* __restrict__ o2e) {
  __shared__ float tile[32][33];
  const int t = blockIdx.x;  // 4 x 4096 tiles of 32x32
  const float* src; unsigned short* dst; int R, C, tl;
  if (t < 4096)       { src = w1r; dst = o1r; R = D_; C = H_; tl = t; }
  else if (t < 8192)  { src = w1e; dst = o1e; R = D_; C = H_; tl = t - 4096; }
  else if (t < 12288) { src = w2r; dst = o2r; R = H_; C = D_; tl = t - 8192; }
  else                { src = w2e; dst = o2e; R = H_; C = D_; tl = t - 12288; }
  const int tc = C >> 5;
  const int r0 = (tl / tc) * 32, c0 = (tl % tc) * 32;
  const int tx = threadIdx.x & 31, ty = threadIdx.x >> 5;  // ty in [0,8)
#pragma unroll
  for (int i = 0; i < 32; i += 8)
    tile[ty + i][tx] = src[(size_t)(r0 + ty + i) * C + c0 + tx];
  __syncthreads();
#pragma unroll
  for (int i = 0; i < 32; i += 8)
    dst[(size_t)(c0 + ty + i) * R + r0 + tx] = f2bf(tile[tx][ty + i]);
}

// ---------------- stable compaction: rgb tokens first, expr at 128-aligned base
__global__ __launch_bounds__(256) void compact_kernel(
    const int* __restrict__ mask, int* __restrict__ perm, int* __restrict__ counts) {
  const int NT = 256, CH = NTOK / NT;  // 64 per thread
  __shared__ int sm[NTOK];
  __shared__ int wsum[4];
  const int t = threadIdx.x;
  const int ln = t & 63, wv = t >> 6;
  for (int i = t; i < NTOK; i += NT) sm[i] = mask[i];       // coalesced
  for (int i = t; i < MPAD; i += NT) perm[i] = -1;          // gaps stay -1
  __syncthreads();
  const int base = t * CH;
  int cnt = 0;
  for (int i = 0; i < CH; ++i) cnt += (sm[base + i] != 0);
  int sc = cnt;
#pragma unroll
  for (int o = 1; o < 64; o <<= 1) {
    int u = __shfl_up(sc, o, 64);
    if (ln >= o) sc += u;
  }
  if (ln == 63) wsum[wv] = sc;
  __syncthreads();
  int woff = 0;
#pragma unroll
  for (int j = 0; j < 4; ++j) woff += (j < wv) ? wsum[j] : 0;
  const int total1 = wsum[0] + wsum[1] + wsum[2] + wsum[3];
  if (t == 0) { counts[0] = total1; counts[1] = NTOK - total1; }
  const int excl = woff + sc - cnt;  // rgb tokens before this chunk
  const int expr_base = ((total1 + 127) >> 7) << 7;
  int p1 = excl;
  int p0 = expr_base + (base - excl);
  for (int i = 0; i < CH; ++i) {
    const int idx = base + i;
    if (sm[idx] != 0) perm[p1++] = idx; else perm[p0++] = idx;
  }
}

// ---------------- LayerNorm into compacted bf16 rows ----------------
__global__ __launch_bounds__(256) void ln_kernel(
    const float* __restrict__ x, const int* __restrict__ mask,
    const int* __restrict__ perm,
    const float* __restrict__ g_rgb, const float* __restrict__ b_rgb,
    const float* __restrict__ g_expr, const float* __restrict__ b_expr,
    unsigned short* __restrict__ xln) {
  const int i = blockIdx.x;
  const int t = perm[i];
  if (t < 0) return;
  const int tid = threadIdx.x;
  const float4 v = ((const float4*)(x + (size_t)t * D_))[tid];
  float s = v.x + v.y + v.z + v.w;
  float ss = v.x * v.x + v.y * v.y + v.z * v.z + v.w * v.w;
#pragma unroll
  for (int o = 32; o > 0; o >>= 1) {
    s += __shfl_xor(s, o, 64);
    ss += __shfl_xor(ss, o, 64);
  }
  __shared__ float red[8];
  const int wv = tid >> 6, ln = tid & 63;
  if (ln == 0) { red[wv] = s; red[4 + wv] = ss; }
  __syncthreads();
  s = red[0] + red[1] + red[2] + red[3];
  ss = red[4] + red[5] + red[6] + red[7];
  const float mu = s * (1.0f / D_);
  const float var = ss * (1.0f / D_) - mu * mu;
  const float rs = rsqrtf(var + 1e-5f);
  const bool rgb = mask[t] != 0;
  const float4 gv = ((const float4*)(rgb ? g_rgb : g_expr))[tid];
  const float4 bv = ((const float4*)(rgb ? b_rgb : b_expr))[tid];
  const unsigned short o0 = f2bf((v.x - mu) * rs * gv.x + bv.x);
  const unsigned short o1 = f2bf((v.y - mu) * rs * gv.y + bv.y);
  const unsigned short o2 = f2bf((v.z - mu) * rs * gv.z + bv.z);
  const unsigned short o3 = f2bf((v.w - mu) * rs * gv.w + bv.w);
  uint2 pk;
  pk.x = (unsigned)o0 | ((unsigned)o1 << 16);
  pk.y = (unsigned)o2 | ((unsigned)o3 << 16);
  *((uint2*)(xln + (size_t)i * D_ + tid * 4)) = pk;
}

// ---------------- m97-style 128x128x(BK=64) bf16 GEMM, B^T layout ----------------
// LDS XOR-swizzled at 16B-chunk granularity (round 3: bank conflicts -> 0).
// Round 5: hoisted all swizzled address math out of the K-loop.
// Round 6 (this round): hoisted state as 32-bit BYTE OFFSETS from wave-uniform
// SGPR bases instead of 64-bit flat pointers — same addresses, ~40 fewer VGPRs
// of address state (8 staging + 16 fragment pointers were 2 VGPRs each).
// Max offset: 16640*4096*2 = 136MB < 2^31, so int is safe.
// XCD-compact block mapping (round 4): xcd = id&7 owns a contiguous m-band.
// EP==0: C = gelu(A*W + bias) -> bf16 h[row*N + col]         (compact rows)
// EP==1: C = A*W + bias       -> fp32 out[perm[row]*N + col] (scatter, fp16-rounded)
template <int EP, int K, int N>
__global__ __launch_bounds__(256) void gemm_kernel(
    const unsigned short* __restrict__ A,       // MPAD x K, bf16 bits
    const unsigned short* __restrict__ Wt_rgb,  // N x K, bf16 bits
    const unsigned short* __restrict__ Wt_expr, // N x K
    const float* __restrict__ bias_rgb,
    const float* __restrict__ bias_expr,
    const int* __restrict__ counts,
    const int* __restrict__ perm,
    void* __restrict__ OutP) {
  constexpr int BM = 128, BN = 128, BK = 64;
  constexpr int MT = MPAD / BM;   // 129
  constexpr int NT = N / BN;      // 32 (gemm1) / 8 (gemm2)
  const int tid = threadIdx.x;
  const int id = blockIdx.x;
  const int xcd = id & 7;
  const int slot = id >> 3;
  const int p = xcd * ((MT * NT) / 8) + slot;
  const int m0 = (p / NT) * BM;
  const int n0 = (p % NT) * BN;
  const int cnt_rgb = counts[0];
  const unsigned short* Wt = (m0 < cnt_rgb) ? Wt_rgb : Wt_expr;
  const float* bias = (m0 < cnt_rgb) ? bias_rgb : bias_expr;

  __shared__ unsigned short As[BM * BK];  // swizzled [m][k]
  __shared__ unsigned short Bs[BN * BK];  // swizzled [n][k]

  f32x4 acc[4][4] = {};

  const int lane = tid & 63, wave = tid >> 6;
  const int wm = (wave & 1) * 64, wn = (wave >> 1) * 64;
  const int quad = lane >> 4, l16 = lane & 15;

  // wave-uniform bases (SGPR); all per-lane state is a 32-bit byte offset
  const char* Abase = (const char*)A;
  const char* Wbase = (const char*)Wt;
  const char* AsB = (const char*)As;
  const char* BsB = (const char*)Bs;

  // hoisted staging offsets (advance by BK*2 bytes per k-iter) and LDS dests
  int ag[4], bg[4], sl[4];
#pragma unroll
  for (int it = 0; it < 4; ++it) {
    const int s = it * 256 + tid;
    const int row = s >> 3;
    const int ks = ((s ^ row) & 7) * 8;  // chunk col (s&7) holds global chunk (s^row)&7
    ag[it] = ((m0 + row) * K + ks) * 2;
    bg[it] = ((n0 + row) * K + ks) * 2;
    sl[it] = s * 16;
  }
  // hoisted swizzled fragment byte-offsets: k0-invariant (2 kk-phases x 4 frags)
  int aoff[2][4], boff[2][4];
#pragma unroll
  for (int hh = 0; hh < 2; ++hh) {
    const int cb = hh * 4 + quad;
#pragma unroll
    for (int mi = 0; mi < 4; ++mi) {
      const int row = wm + mi * 16 + l16;
      aoff[hh][mi] = (row * BK + (((cb ^ row) & 7) << 3)) * 2;
    }
#pragma unroll
    for (int ni = 0; ni < 4; ++ni) {
      const int row = wn + ni * 16 + l16;
      boff[hh][ni] = (row * BK + (((cb ^ row) & 7) << 3)) * 2;
    }
  }

  for (int k0 = 0; k0 < K; k0 += BK) {
#pragma unroll
    for (int it = 0; it < 4; ++it) {
      gld16(Abase + ag[it], (void*)(AsB + sl[it]));
      gld16(Wbase + bg[it], (void*)(BsB + sl[it]));
      ag[it] += BK * 2;
      bg[it] += BK * 2;
    }
    __syncthreads();
#pragma unroll
    for (int hh = 0; hh < 2; ++hh) {
      bf16x8 a[4], b[4];
#pragma unroll
      for (int mi = 0; mi < 4; ++mi) a[mi] = *(const bf16x8*)(AsB + aoff[hh][mi]);
#pragma unroll
      for (int ni = 0; ni < 4; ++ni) b[ni] = *(const bf16x8*)(BsB + boff[hh][ni]);
#pragma unroll
      for (int mi = 0; mi < 4; ++mi)
#pragma unroll
        for (int ni = 0; ni < 4; ++ni)
          acc[mi][ni] = __builtin_amdgcn_mfma_f32_16x16x32_bf16(a[mi], b[ni], acc[mi][ni], 0, 0, 0);
    }
    __syncthreads();
  }

  // epilogue: C/D layout col = lane&15, row = quad*4 + r  [m89/m91-verified]
  float bv[4];
#pragma unroll
  for (int ni = 0; ni < 4; ++ni) bv[ni] = bias[n0 + wn + ni * 16 + l16];

#pragma unroll
  for (int mi = 0; mi < 4; ++mi) {
#pragma unroll
    for (int r = 0; r < 4; ++r) {
      const int row = m0 + wm + mi * 16 + quad * 4 + r;
      if (EP == 0) {
        // gap rows read poisoned-but-finite xln; store unconditionally (never scattered)
        unsigned short* orow = (unsigned short*)OutP + (size_t)row * N + n0 + wn + l16;
#pragma unroll
        for (int ni = 0; ni < 4; ++ni) {
          orow[ni * 16] = f2bf(gelu_fast(acc[mi][ni][r] + bv[ni]));
        }
      } else {
        const int p2 = perm[row];
        if (p2 < 0) continue;
        // reference output is z.astype(float16); d_out is an fp32 buffer
        float* orow = (float*)OutP + (size_t)p2 * N + n0 + wn + l16;
#pragma unroll
        for (int ni = 0; ni < 4; ++ni) {
          float v = acc[mi][ni][r] + bv[ni];
          orow[ni * 16] = __half2float(__float2half_rn(v));
        }
      }
    }
  }
}

extern "C" void kernel_launch(void* const* d_in, const int* in_sizes, int n_in,
                              void* d_out, int out_size, void* d_ws, size_t ws_size,
                              hipStream_t stream) {
  const float* x       = (const float*)d_in[0];
  const int*   mask    = (const int*)d_in[1];
  const float* g_rgb   = (const float*)d_in[2];
  const float* b_rgb   = (const float*)d_in[3];
  const float* w1_rgb  = (const float*)d_in[4];
  const float* b1_rgb  = (const float*)d_in[5];
  const float* w2_rgb  = (const float*)d_in[6];
  const float* b2_rgb  = (const float*)d_in[7];
  const float* g_expr  = (const float*)d_in[8];
  const float* b_expr  = (const float*)d_in[9];
  const float* w1_expr = (const float*)d_in[10];
  const float* b1_expr = (const float*)d_in[11];
  const float* w2_expr = (const float*)d_in[12];
  const float* b2_expr = (const float*)d_in[13];

  char* w = (char*)d_ws;
  int* counts               = (int*)(w + 0);
  int* perm                 = (int*)(w + 256);
  unsigned short* w1t_rgb   = (unsigned short*)(w + 66560);
  unsigned short* w1t_expr  = (unsigned short*)(w + 8455168);
  unsigned short* w2t_rgb   = (unsigned short*)(w + 16843776);
  unsigned short* w2t_expr  = (unsigned short*)(w + 25232384);
  unsigned short* xln       = (unsigned short*)(w + 33620992);  // MPAD x 1024 bf16
  unsigned short* h         = (unsigned short*)(w + 67437568);  // MPAD x 4096 bf16
  // total ws use: 202,703,872 bytes

  // 1) stable expert compaction
  compact_kernel<<<1, 256, 0, stream>>>(mask, perm, counts);

  // 2) weight transpose+convert (all 4 in one launch): W (KxN fp32) -> Wt (NxK bf16)
  transpose4_kernel<<<16384, 256, 0, stream>>>(
      w1_rgb, w1_expr, w2_rgb, w2_expr, w1t_rgb, w1t_expr, w2t_rgb, w2t_expr);

  // 3) LayerNorm into compacted rows
  ln_kernel<<<MPAD, 256, 0, stream>>>(x, mask, perm, g_rgb, b_rgb, g_expr, b_expr, xln);

  // 4) h = gelu(xln @ w1 + b1)   (M=MPAD, K=1024, N=4096)
  gemm_kernel<0, D_, H_><<<dim3((H_ / 128) * (MPAD / 128)), 256, 0, stream>>>(
      xln, w1t_rgb, w1t_expr, b1_rgb, b1_expr, counts, perm, h);

  // 5) out[tok] = h @ w2 + b2    (M=MPAD, K=4096, N=1024), scatter via perm, fp32 out
  gemm_kernel<1, H_, D_><<<dim3((D_ / 128) * (MPAD / 128)), 256, 0, stream>>>(
      h, w2t_rgb, w2t_expr, b2_rgb, b2_expr, counts, perm, d_out);
}

// Round 2
// 574.638 us; speedup vs baseline: 1.0302x; 1.0302x over previous
//
#include <hip/hip_runtime.h>
#include <hip/hip_bf16.h>
#include <hip/hip_fp16.h>

#define D_ 1024
#define H_ 4096
#define NTOK 16384
#define MPAD 16640  // NTOK + 256 (256-aligned expert boundary so 256-row tiles are single-expert)

typedef __attribute__((ext_vector_type(8))) short bf16x8;
typedef __attribute__((ext_vector_type(4))) float f32x4;

static __device__ __forceinline__ unsigned short f2bf(float f) {
  union { float f; unsigned u; } x; x.f = f;
  unsigned u = x.u + 0x7fffu + ((x.u >> 16) & 1u);  // RNE
  return (unsigned short)(u >> 16);
}

static __device__ __forceinline__ void gld16(const void* g, void* l) {
  __builtin_amdgcn_global_load_lds(
      (const __attribute__((address_space(1))) unsigned int*)g,
      (__attribute__((address_space(3))) unsigned int*)l, 16, 0, 0);
}

// tanh-form gelu reduced to x*sigmoid(2c(x+0.044715x^3)); |err vs exact| ~1e-3
static __device__ __forceinline__ float gelu_fast(float x) {
  const float z = x * (1.5957691216f + 0.0713548163f * x * x);
  return x * __builtin_amdgcn_rcpf(1.0f + __expf(-z));
}

// ---------------- merged transpose fp32 (R x C) -> bf16 (C x R), 4 matrices ----
__global__ __launch_bounds__(256) void transpose4_kernel(
    const float* __restrict__ w1r, const float* __restrict__ w1e,
    const float* __restrict__ w2r, const float* __restrict__ w2e,
    unsigned short* __restrict__ o1r, unsigned short* __restrict__ o1e,
    unsigned short* __restrict__ o2r, unsigned short* __restrict__ o2e) {
  __shared__ float tile[32][33];
  const int t = blockIdx.x;  // 4 x 4096 tiles of 32x32
  const float* src; unsigned short* dst; int R, C, tl;
  if (t < 4096)       { src = w1r; dst = o1r; R = D_; C = H_; tl = t; }
  else if (t < 8192)  { src = w1e; dst = o1e; R = D_; C = H_; tl = t - 4096; }
  else if (t < 12288) { src = w2r; dst = o2r; R = H_; C = D_; tl = t - 8192; }
  else                { src = w2e; dst = o2e; R = H_; C = D_; tl = t - 12288; }
  const int tc = C >> 5;
  const int r0 = (tl / tc) * 32, c0 = (tl % tc) * 32;
  const int tx = threadIdx.x & 31, ty = threadIdx.x >> 5;  // ty in [0,8)
#pragma unroll
  for (int i = 0; i < 32; i += 8)
    tile[ty + i][tx] = src[(size_t)(r0 + ty + i) * C + c0 + tx];
  __syncthreads();
#pragma unroll
  for (int i = 0; i < 32; i += 8)
    dst[(size_t)(c0 + ty + i) * R + r0 + tx] = f2bf(tile[tx][ty + i]);
}

// ---------------- stable compaction: rgb tokens first, expr at 256-aligned base
__global__ __launch_bounds__(256) void compact_kernel(
    const int* __restrict__ mask, int* __restrict__ perm, int* __restrict__ counts) {
  const int NT = 256, CH = NTOK / NT;  // 64 per thread
  __shared__ int sm[NTOK];
  __shared__ int wsum[4];
  const int t = threadIdx.x;
  const int ln = t & 63, wv = t >> 6;
  for (int i = t; i < NTOK; i += NT) sm[i] = mask[i];       // coalesced
  for (int i = t; i < MPAD; i += NT) perm[i] = -1;          // gaps stay -1
  __syncthreads();
  const int base = t * CH;
  int cnt = 0;
  for (int i = 0; i < CH; ++i) cnt += (sm[base + i] != 0);
  int sc = cnt;
#pragma unroll
  for (int o = 1; o < 64; o <<= 1) {
    int u = __shfl_up(sc, o, 64);
    if (ln >= o) sc += u;
  }
  if (ln == 63) wsum[wv] = sc;
  __syncthreads();
  int woff = 0;
#pragma unroll
  for (int j = 0; j < 4; ++j) woff += (j < wv) ? wsum[j] : 0;
  const int total1 = wsum[0] + wsum[1] + wsum[2] + wsum[3];
  if (t == 0) { counts[0] = total1; counts[1] = NTOK - total1; }
  const int excl = woff + sc - cnt;  // rgb tokens before this chunk
  const int expr_base = ((total1 + 255) >> 8) << 8;  // 256-aligned boundary
  int p1 = excl;
  int p0 = expr_base + (base - excl);
  for (int i = 0; i < CH; ++i) {
    const int idx = base + i;
    if (sm[idx] != 0) perm[p1++] = idx; else perm[p0++] = idx;
  }
}

// ---------------- LayerNorm into compacted bf16 rows ----------------
__global__ __launch_bounds__(256) void ln_kernel(
    const float* __restrict__ x, const int* __restrict__ mask,
    const int* __restrict__ perm,
    const float* __restrict__ g_rgb, const float* __restrict__ b_rgb,
    const float* __restrict__ g_expr, const float* __restrict__ b_expr,
    unsigned short* __restrict__ xln) {
  const int i = blockIdx.x;
  const int t = perm[i];
  if (t < 0) return;
  const int tid = threadIdx.x;
  const float4 v = ((const float4*)(x + (size_t)t * D_))[tid];
  float s = v.x + v.y + v.z + v.w;
  float ss = v.x * v.x + v.y * v.y + v.z * v.z + v.w * v.w;
#pragma unroll
  for (int o = 32; o > 0; o >>= 1) {
    s += __shfl_xor(s, o, 64);
    ss += __shfl_xor(ss, o, 64);
  }
  __shared__ float red[8];
  const int wv = tid >> 6, ln = tid & 63;
  if (ln == 0) { red[wv] = s; red[4 + wv] = ss; }
  __syncthreads();
  s = red[0] + red[1] + red[2] + red[3];
  ss = red[4] + red[5] + red[6] + red[7];
  const float mu = s * (1.0f / D_);
  const float var = ss * (1.0f / D_) - mu * mu;
  const float rs = rsqrtf(var + 1e-5f);
  const bool rgb = mask[t] != 0;
  const float4 gv = ((const float4*)(rgb ? g_rgb : g_expr))[tid];
  const float4 bv = ((const float4*)(rgb ? b_rgb : b_expr))[tid];
  const unsigned short o0 = f2bf((v.x - mu) * rs * gv.x + bv.x);
  const unsigned short o1 = f2bf((v.y - mu) * rs * gv.y + bv.y);
  const unsigned short o2 = f2bf((v.z - mu) * rs * gv.z + bv.z);
  const unsigned short o3 = f2bf((v.w - mu) * rs * gv.w + bv.w);
  uint2 pk;
  pk.x = (unsigned)o0 | ((unsigned)o1 << 16);
  pk.y = (unsigned)o2 | ((unsigned)o3 << 16);
  *((uint2*)(xln + (size_t)i * D_ + tid * 4)) = pk;
}

// =================================================================
// 256x256x(BK=64) 8-phase bf16 GEMM (m201-template port), GEMM1 only.
// 512 threads = 8 waves (2M x 4N), per-wave C = 128x64.
// LDS 128 KiB: As[2][256][64] + Bs[2][256][64], 16B-chunk XOR swizzle
// (identical swizzle math to the verified 128^2 kernel).
// Per K-tile t (parity P): 4 phases, each {ds_read subtile | stage half-tile |
// s_barrier | setprio(1) 16xMFMA setprio(0) | s_barrier}.
// Staging liveness: A-halves of t+1 -> As[P^1] at phases 1,2 (dead since t-1 P4);
// B-halves of t+2 -> Bs[P] at phase 4 (dead after t's P3 barrier2, since P3's
// ds_reads returned before its post-MFMA barrier).
// vmcnt(4) once per K-tile before the final barrier: confirms A(t+1)+B(t+1),
// leaves the just-issued B(t+2) pair (4 loads/wave) in flight — never drains.
// C = gelu(A*W + bias) -> bf16 h[row*N + col]
// =================================================================
template <int K, int N>
__global__ __launch_bounds__(512, 2) void gemm8_kernel(
    const unsigned short* __restrict__ A,       // MPAD x K bf16 bits
    const unsigned short* __restrict__ Wt_rgb,  // N x K bf16 bits
    const unsigned short* __restrict__ Wt_expr, // N x K
    const float* __restrict__ bias_rgb,
    const float* __restrict__ bias_expr,
    const int* __restrict__ counts,
    unsigned short* __restrict__ Out) {
  constexpr int MT = MPAD / 256;  // 65
  constexpr int NT = N / 256;     // 16
  constexpr int ntk = K / 64;     // 16
  constexpr int KH2 = 128 * K * 2;  // byte stride of a 128-row half in A/W

  const int tid = threadIdx.x;
  const int id = blockIdx.x;
  const int xcd = id & 7;
  const int slot = id >> 3;
  const int p = xcd * ((MT * NT) / 8) + slot;  // bijective, 1040 % 8 == 0
  const int m0 = (p / NT) * 256;
  const int n0 = (p % NT) * 256;
  const int cnt_rgb = counts[0];
  const unsigned short* Wt = (m0 < cnt_rgb) ? Wt_rgb : Wt_expr;
  const float* bias = (m0 < cnt_rgb) ? bias_rgb : bias_expr;

  __shared__ unsigned short As[2][256 * 64];
  __shared__ unsigned short Bs[2][256 * 64];

  const int lane = tid & 63, wave = tid >> 6;
  const int wr = wave >> 2, wc = wave & 3;   // 2M x 4N waves
  const int quad = lane >> 4, l16 = lane & 15;

  f32x4 acc[8][4] = {};

  const char* Abase = (const char*)A;
  const char* Wbase = (const char*)Wt;

  // staging offsets: s in [0,1024) covers one 128x64 half-tile (8 chunks/row)
  int agK0, agK1, bgK0, bgK1, sl0, sl1;
  {
    const int s0 = tid, s1 = 512 + tid;
    const int r0 = s0 >> 3, r1 = s1 >> 3;
    const int ks0 = ((s0 ^ r0) & 7) * 8, ks1 = ((s1 ^ r1) & 7) * 8;
    agK0 = ((m0 + r0) * K + ks0) * 2;  agK1 = ((m0 + r1) * K + ks1) * 2;
    bgK0 = ((n0 + r0) * K + ks0) * 2;  bgK1 = ((n0 + r1) * K + ks1) * 2;
    sl0 = s0 * 16;  sl1 = s1 * 16;
  }

  // hoisted swizzled ds_read byte offsets (tile-base added via literal P*32768)
  int aoffL[2][2][4];  // [kk][mhalf][mi]
  int boffL[2][4];     // [kk][ni]
#pragma unroll
  for (int kk = 0; kk < 2; ++kk) {
    const int cb = kk * 4 + quad;
#pragma unroll
    for (int mh = 0; mh < 2; ++mh)
#pragma unroll
      for (int mi = 0; mi < 4; ++mi) {
        const int row = wr * 128 + mh * 64 + mi * 16 + l16;
        aoffL[kk][mh][mi] = (row * 64 + ((cb ^ row) & 7) * 8) * 2;
      }
#pragma unroll
    for (int ni = 0; ni < 4; ++ni) {
      const int row = wc * 64 + ni * 16 + l16;
      boffL[kk][ni] = (row * 64 + ((cb ^ row) & 7) * 8) * 2;
    }
  }

  bf16x8 a0, a1, a2, a3;
  bf16x8 bb[4];

#define STAGE_A(T1, HA, Q) do { \
    gld16(Abase + agK0 + (HA) * KH2 + (T1) * 128, (char*)As + (Q) * 32768 + (HA) * 16384 + sl0); \
    gld16(Abase + agK1 + (HA) * KH2 + (T1) * 128, (char*)As + (Q) * 32768 + (HA) * 16384 + sl1); \
  } while (0)
#define STAGE_B(T2, HB, Q) do { \
    gld16(Wbase + bgK0 + (HB) * KH2 + (T2) * 128, (char*)Bs + (Q) * 32768 + (HB) * 16384 + sl0); \
    gld16(Wbase + bgK1 + (HB) * KH2 + (T2) * 128, (char*)Bs + (Q) * 32768 + (HB) * 16384 + sl1); \
  } while (0)
#define RD_A(P_, KK, MH) do { \
    const char* _ab = (const char*)As + (P_) * 32768; \
    a0 = *(const bf16x8*)(_ab + aoffL[KK][MH][0]); \
    a1 = *(const bf16x8*)(_ab + aoffL[KK][MH][1]); \
    a2 = *(const bf16x8*)(_ab + aoffL[KK][MH][2]); \
    a3 = *(const bf16x8*)(_ab + aoffL[KK][MH][3]); \
  } while (0)
#define RD_B(P_, KK) do { \
    const char* _bp = (const char*)Bs + (P_) * 32768; \
    bb[0] = *(const bf16x8*)(_bp + boffL[KK][0]); \
    bb[1] = *(const bf16x8*)(_bp + boffL[KK][1]); \
    bb[2] = *(const bf16x8*)(_bp + boffL[KK][2]); \
    bb[3] = *(const bf16x8*)(_bp + boffL[KK][3]); \
  } while (0)
#define MFMA16(MO) do { \
    acc[(MO)+0][0] = __builtin_amdgcn_mfma_f32_16x16x32_bf16(a0, bb[0], acc[(MO)+0][0], 0, 0, 0); \
    acc[(MO)+0][1] = __builtin_amdgcn_mfma_f32_16x16x32_bf16(a0, bb[1], acc[(MO)+0][1], 0, 0, 0); \
    acc[(MO)+0][2] = __builtin_amdgcn_mfma_f32_16x16x32_bf16(a0, bb[2], acc[(MO)+0][2], 0, 0, 0); \
    acc[(MO)+0][3] = __builtin_amdgcn_mfma_f32_16x16x32_bf16(a0, bb[3], acc[(MO)+0][3], 0, 0, 0); \
    acc[(MO)+1][0] = __builtin_amdgcn_mfma_f32_16x16x32_bf16(a1, bb[0], acc[(MO)+1][0], 0, 0, 0); \
    acc[(MO)+1][1] = __builtin_amdgcn_mfma_f32_16x16x32_bf16(a1, bb[1], acc[(MO)+1][1], 0, 0, 0); \
    acc[(MO)+1][2] = __builtin_amdgcn_mfma_f32_16x16x32_bf16(a1, bb[2], acc[(MO)+1][2], 0, 0, 0); \
    acc[(MO)+1][3] = __builtin_amdgcn_mfma_f32_16x16x32_bf16(a1, bb[3], acc[(MO)+1][3], 0, 0, 0); \
    acc[(MO)+2][0] = __builtin_amdgcn_mfma_f32_16x16x32_bf16(a2, bb[0], acc[(MO)+2][0], 0, 0, 0); \
    acc[(MO)+2][1] = __builtin_amdgcn_mfma_f32_16x16x32_bf16(a2, bb[1], acc[(MO)+2][1], 0, 0, 0); \
    acc[(MO)+2][2] = __builtin_amdgcn_mfma_f32_16x16x32_bf16(a2, bb[2], acc[(MO)+2][2], 0, 0, 0); \
    acc[(MO)+2][3] = __builtin_amdgcn_mfma_f32_16x16x32_bf16(a2, bb[3], acc[(MO)+2][3], 0, 0, 0); \
    acc[(MO)+3][0] = __builtin_amdgcn_mfma_f32_16x16x32_bf16(a3, bb[0], acc[(MO)+3][0], 0, 0, 0); \
    acc[(MO)+3][1] = __builtin_amdgcn_mfma_f32_16x16x32_bf16(a3, bb[1], acc[(MO)+3][1], 0, 0, 0); \
    acc[(MO)+3][2] = __builtin_amdgcn_mfma_f32_16x16x32_bf16(a3, bb[2], acc[(MO)+3][2], 0, 0, 0); \
    acc[(MO)+3][3] = __builtin_amdgcn_mfma_f32_16x16x32_bf16(a3, bb[3], acc[(MO)+3][3], 0, 0, 0); \
  } while (0)

#define KTILE(T_, P_, SA_, SB_, VMC_) do { \
    /* phase 1 */ \
    RD_B(P_, 0); RD_A(P_, 0, 0); \
    if (SA_) STAGE_A((T_) + 1, 0, (P_) ^ 1); \
    __builtin_amdgcn_s_barrier(); \
    __builtin_amdgcn_s_setprio(1); MFMA16(0); __builtin_amdgcn_s_setprio(0); \
    __builtin_amdgcn_s_barrier(); \
    /* phase 2 */ \
    RD_A(P_, 0, 1); \
    if (SA_) STAGE_A((T_) + 1, 1, (P_) ^ 1); \
    __builtin_amdgcn_s_barrier(); \
    __builtin_amdgcn_s_setprio(1); MFMA16(4); __builtin_amdgcn_s_setprio(0); \
    __builtin_amdgcn_s_barrier(); \
    /* phase 3 */ \
    RD_B(P_, 1); RD_A(P_, 1, 0); \
    __builtin_amdgcn_s_barrier(); \
    __builtin_amdgcn_s_setprio(1); MFMA16(0); __builtin_amdgcn_s_setprio(0); \
    __builtin_amdgcn_s_barrier(); \
    /* phase 4 */ \
    RD_A(P_, 1, 1); \
    if (SB_) { STAGE_B((T_) + 2, 0, P_); STAGE_B((T_) + 2, 1, P_); } \
    __builtin_amdgcn_s_barrier(); \
    __builtin_amdgcn_s_setprio(1); MFMA16(4); __builtin_amdgcn_s_setprio(0); \
    if ((VMC_) == 4) { asm volatile("s_waitcnt vmcnt(4)" ::: "memory"); } \
    else if ((VMC_) == 0) { asm volatile("s_waitcnt vmcnt(0)" ::: "memory"); } \
    __builtin_amdgcn_sched_barrier(0); \
    __builtin_amdgcn_s_barrier(); \
  } while (0)

  // prologue: A0 -> As[0], B0 -> Bs[0], B1 -> Bs[1]; keep B1 (4 loads) in flight
  STAGE_A(0, 0, 0); STAGE_A(0, 1, 0);
  STAGE_B(0, 0, 0); STAGE_B(0, 1, 0);
  STAGE_B(1, 0, 1); STAGE_B(1, 1, 1);
  asm volatile("s_waitcnt vmcnt(4)" ::: "memory");
  __builtin_amdgcn_sched_barrier(0);
  __builtin_amdgcn_s_barrier();

  for (int tt = 0; tt < ntk / 2 - 1; ++tt) {
    const int t0 = tt * 2;
    KTILE(t0, 0, 1, 1, 4);
    KTILE(t0 + 1, 1, 1, 1, 4);
  }
  KTILE(ntk - 2, 0, 1, 0, 0);   // stages A[ntk-1]; drain before last tile
  KTILE(ntk - 1, 1, 0, 0, -1);  // no staging, no wait

#undef KTILE
#undef MFMA16
#undef RD_B
#undef RD_A
#undef STAGE_B
#undef STAGE_A

  // epilogue: C/D layout col = lane&15, row = quad*4 + r  [m89/m91-verified]
  float bv[4];
#pragma unroll
  for (int ni = 0; ni < 4; ++ni) bv[ni] = bias[n0 + wc * 64 + ni * 16 + l16];
#pragma unroll
  for (int mi = 0; mi < 8; ++mi) {
#pragma unroll
    for (int r = 0; r < 4; ++r) {
      const int row = m0 + wr * 128 + mi * 16 + quad * 4 + r;
      unsigned short* orow = Out + (size_t)row * N + n0 + wc * 64 + l16;
#pragma unroll
      for (int ni = 0; ni < 4; ++ni)
        orow[ni * 16] = f2bf(gelu_fast(acc[mi][ni][r] + bv[ni]));
    }
  }
}

// ---------------- m97-style 128x128x(BK=64) bf16 GEMM (kept for GEMM2) ------
// EP==1: C = A*W + bias -> fp32 out[perm[row]*N + col] (scatter, fp16-rounded)
template <int EP, int K, int N>
__global__ __launch_bounds__(256) void gemm_kernel(
    const unsigned short* __restrict__ A,
    const unsigned short* __restrict__ Wt_rgb,
    const unsigned short* __restrict__ Wt_expr,
    const float* __restrict__ bias_rgb,
    const float* __restrict__ bias_expr,
    const int* __restrict__ counts,
    const int* __restrict__ perm,
    void* __restrict__ OutP) {
  constexpr int BM = 128, BN = 128, BK = 64;
  constexpr int MT = MPAD / BM;   // 130
  constexpr int NT = N / BN;
  const int tid = threadIdx.x;
  const int id = blockIdx.x;
  const int xcd = id & 7;
  const int slot = id >> 3;
  const int p = xcd * ((MT * NT) / 8) + slot;
  const int m0 = (p / NT) * BM;
  const int n0 = (p % NT) * BN;
  const int cnt_rgb = counts[0];
  const unsigned short* Wt = (m0 < cnt_rgb) ? Wt_rgb : Wt_expr;
  const float* bias = (m0 < cnt_rgb) ? bias_rgb : bias_expr;

  __shared__ unsigned short As[BM * BK];
  __shared__ unsigned short Bs[BN * BK];

  f32x4 acc[4][4] = {};

  const int lane = tid & 63, wave = tid >> 6;
  const int wm = (wave & 1) * 64, wn = (wave >> 1) * 64;
  const int quad = lane >> 4, l16 = lane & 15;

  const char* Abase = (const char*)A;
  const char* Wbase = (const char*)Wt;
  const char* AsB = (const char*)As;
  const char* BsB = (const char*)Bs;

  int ag[4], bg[4], sl[4];
#pragma unroll
  for (int it = 0; it < 4; ++it) {
    const int s = it * 256 + tid;
    const int row = s >> 3;
    const int ks = ((s ^ row) & 7) * 8;
    ag[it] = ((m0 + row) * K + ks) * 2;
    bg[it] = ((n0 + row) * K + ks) * 2;
    sl[it] = s * 16;
  }
  int aoff[2][4], boff[2][4];
#pragma unroll
  for (int hh = 0; hh < 2; ++hh) {
    const int cb = hh * 4 + quad;
#pragma unroll
    for (int mi = 0; mi < 4; ++mi) {
      const int row = wm + mi * 16 + l16;
      aoff[hh][mi] = (row * BK + (((cb ^ row) & 7) << 3)) * 2;
    }
#pragma unroll
    for (int ni = 0; ni < 4; ++ni) {
      const int row = wn + ni * 16 + l16;
      boff[hh][ni] = (row * BK + (((cb ^ row) & 7) << 3)) * 2;
    }
  }

  for (int k0 = 0; k0 < K; k0 += BK) {
#pragma unroll
    for (int it = 0; it < 4; ++it) {
      gld16(Abase + ag[it], (void*)(AsB + sl[it]));
      gld16(Wbase + bg[it], (void*)(BsB + sl[it]));
      ag[it] += BK * 2;
      bg[it] += BK * 2;
    }
    __syncthreads();
#pragma unroll
    for (int hh = 0; hh < 2; ++hh) {
      bf16x8 a[4], b[4];
#pragma unroll
      for (int mi = 0; mi < 4; ++mi) a[mi] = *(const bf16x8*)(AsB + aoff[hh][mi]);
#pragma unroll
      for (int ni = 0; ni < 4; ++ni) b[ni] = *(const bf16x8*)(BsB + boff[hh][ni]);
#pragma unroll
      for (int mi = 0; mi < 4; ++mi)
#pragma unroll
        for (int ni = 0; ni < 4; ++ni)
          acc[mi][ni] = __builtin_amdgcn_mfma_f32_16x16x32_bf16(a[mi], b[ni], acc[mi][ni], 0, 0, 0);
    }
    __syncthreads();
  }

  float bv[4];
#pragma unroll
  for (int ni = 0; ni < 4; ++ni) bv[ni] = bias[n0 + wn + ni * 16 + l16];

#pragma unroll
  for (int mi = 0; mi < 4; ++mi) {
#pragma unroll
    for (int r = 0; r < 4; ++r) {
      const int row = m0 + wm + mi * 16 + quad * 4 + r;
      if (EP == 0) {
        unsigned short* orow = (unsigned short*)OutP + (size_t)row * N + n0 + wn + l16;
#pragma unroll
        for (int ni = 0; ni < 4; ++ni) {
          orow[ni * 16] = f2bf(gelu_fast(acc[mi][ni][r] + bv[ni]));
        }
      } else {
        const int p2 = perm[row];
        if (p2 < 0) continue;
        float* orow = (float*)OutP + (size_t)p2 * N + n0 + wn + l16;
#pragma unroll
        for (int ni = 0; ni < 4; ++ni) {
          float v = acc[mi][ni][r] + bv[ni];
          orow[ni * 16] = __half2float(__float2half_rn(v));
        }
      }
    }
  }
}

extern "C" void kernel_launch(void* const* d_in, const int* in_sizes, int n_in,
                              void* d_out, int out_size, void* d_ws, size_t ws_size,
                              hipStream_t stream) {
  const float* x       = (const float*)d_in[0];
  const int*   mask    = (const int*)d_in[1];
  const float* g_rgb   = (const float*)d_in[2];
  const float* b_rgb   = (const float*)d_in[3];
  const float* w1_rgb  = (const float*)d_in[4];
  const float* b1_rgb  = (const float*)d_in[5];
  const float* w2_rgb  = (const float*)d_in[6];
  const float* b2_rgb  = (const float*)d_in[7];
  const float* g_expr  = (const float*)d_in[8];
  const float* b_expr  = (const float*)d_in[9];
  const float* w1_expr = (const float*)d_in[10];
  const float* b1_expr = (const float*)d_in[11];
  const float* w2_expr = (const float*)d_in[12];
  const float* b2_expr = (const float*)d_in[13];

  char* w = (char*)d_ws;
  int* counts               = (int*)(w + 0);
  int* perm                 = (int*)(w + 256);        // 16640*4 -> end 66816
  unsigned short* w1t_rgb   = (unsigned short*)(w + 66816);
  unsigned short* w1t_expr  = (unsigned short*)(w + 8455424);
  unsigned short* w2t_rgb   = (unsigned short*)(w + 16844032);
  unsigned short* w2t_expr  = (unsigned short*)(w + 25232640);
  unsigned short* xln       = (unsigned short*)(w + 33621248);  // MPAD x 1024 bf16
  unsigned short* h         = (unsigned short*)(w + 67699968);  // MPAD x 4096 bf16
  // total ws use: 204,014,848 bytes

  // 1) stable expert compaction (256-aligned boundary)
  compact_kernel<<<1, 256, 0, stream>>>(mask, perm, counts);

  // 2) weight transpose+convert: W (KxN fp32) -> Wt (NxK bf16)
  transpose4_kernel<<<16384, 256, 0, stream>>>(
      w1_rgb, w1_expr, w2_rgb, w2_expr, w1t_rgb, w1t_expr, w2t_rgb, w2t_expr);

  // 3) LayerNorm into compacted rows
  ln_kernel<<<MPAD, 256, 0, stream>>>(x, mask, perm, g_rgb, b_rgb, g_expr, b_expr, xln);

  // 4) h = gelu(xln @ w1 + b1)   (M=MPAD, K=1024, N=4096) — 8-phase 256^2
  gemm8_kernel<D_, H_><<<dim3((MPAD / 256) * (H_ / 256)), 512, 0, stream>>>(
      xln, w1t_rgb, w1t_expr, b1_rgb, b1_expr, counts, h);

  // 5) out[tok] = h @ w2 + b2    (M=MPAD, K=4096, N=1024), scatter via perm
  gemm_kernel<1, H_, D_><<<dim3((D_ / 128) * (MPAD / 128)), 256, 0, stream>>>(
      h, w2t_rgb, w2t_expr, b2_rgb, b2_expr, counts, perm, d_out);
}